// Round 2
// 1371.116 us; speedup vs baseline: 1.2559x; 1.2559x over previous
//
#include <hip/hip_runtime.h>
#include <hip/hip_bf16.h>

// LIF fused kernel, Round 5 (= R4 resubmit; R4 bench was an infra failure:
// "MI355X container failed twice", no counters returned. Source re-audited
// for OOB/hang/alignment — clean.)
//
// Design: bit-packed spike prepass.
// R3 analysis: latency-bound on fp32 spike staging (2900 cy/t; MFMA floor
// ~466 cy/t at 3-term split; ~2000 cy/t stalled on slab loads: 8 MB/t L2
// traffic, 266 MB HBM fetch with ~900 cy first-touch latency, 1 wave/SIMD,
// prefetch depth <1 iteration).
//
// Fix: spikes are exactly {0,1} -> pack to 1 bit/elem in a prepass
// (16 MiB total, L3-resident). Main kernel loads 1 dword/thread/t
// (prefetch depth 2 = ~2 iterations), unpacks bits->bf16 in-register with
// the 0x10001*0x3F80 spread trick, stores the SAME sA layout as R3.
// MFMA / W-split / LIF / output code unchanged (verified numerics:
// bf16(0/1) exact both paths).
//
// Packed layout: bits[t*4096 + b*16 + wd], bit j (LSB first) =
// spike[t][b][wd*32+j] != 0.

typedef __attribute__((ext_vector_type(8))) short short8;   // 8 x bf16
typedef __attribute__((ext_vector_type(4))) float floatx4;
typedef __attribute__((ext_vector_type(2))) unsigned uintx2;
typedef __attribute__((ext_vector_type(4))) unsigned uintx4;

#define T_STEPS 1024
#define B_DIM   256
#define F_DIM   512
#define BF      (B_DIM * F_DIM)
#define ROWP    520   // padded LDS row (bf16 units); 1040B = 16B-aligned rows

static __device__ __forceinline__ unsigned short f2bf_rne(float f) {
    unsigned u = __float_as_uint(f);
    return (unsigned short)((u + 0x7FFFu + ((u >> 16) & 1u)) >> 16);
}
static __device__ __forceinline__ float bf2f(unsigned short h) {
    return __uint_as_float(((unsigned)h) << 16);
}

// ---------------- prepass: fp32 {0,1} -> bitmask ----------------
// Wave handles chunks of 2048 consecutive elements (= 64 output dwords).
// Round r: lane reads elem base + r*64 + lane (coalesced 256B), ballot
// gives 64 bits; lane keeps the dword it will store (lane = 2r -> lo,
// 2r+1 -> hi). 65536 chunks; 2048 blocks x 4 waves, 8 chunks each.
__global__ __launch_bounds__(256)
void pack_kernel(const float* __restrict__ sp, unsigned* __restrict__ bits)
{
    const int lane = threadIdx.x & 63;
    const int wv   = blockIdx.x * 4 + (threadIdx.x >> 6);
    for (int c = wv; c < 65536; c += 2048 * 4) {
        const float* p = sp + (size_t)c * 2048;
        unsigned val = 0;
        #pragma unroll
        for (int r = 0; r < 32; ++r) {
            float x = p[r * 64 + lane];
            unsigned long long m = __ballot(x != 0.0f);
            unsigned sel = (lane & 1) ? (unsigned)(m >> 32) : (unsigned)m;
            if ((lane >> 1) == r) val = sel;
        }
        bits[(size_t)c * 64 + lane] = val;
    }
}

// ---------------- main kernel: bitmask input ----------------
__global__ __launch_bounds__(256, 1)
void lif_kernel_bits(const unsigned* __restrict__ bits,
                     const float* __restrict__ W,
                     float* __restrict__ out)
{
    __shared__ unsigned short sA[16 * ROWP];   // staged bf16 A-slab
    __shared__ float xbuf[2 * 256];            // kh=1 partial x per g-half

    const int tid  = threadIdx.x;
    const int lane = tid & 63;
    const int w    = tid >> 6;      // 0..3
    const int gh   = w & 1;         // g-half within block
    const int kh   = w >> 1;        // K-half
    const int bt   = blockIdx.x & 15;
    const int gb   = blockIdx.x >> 4;
    const int b0   = bt * 16;
    const int gw   = gb * 32 + gh * 16;   // wave's g-base
    const int mrow = lane & 15;
    const int kq   = lane >> 4;

    // ---- W fragments (once): rows gw+mrow, k in kh*256 + ks*32 + kq*8 + j
    short8 whi[8], wmd[8], wlo[8];
    {
        const float* wp = W + (size_t)(gw + mrow) * F_DIM + kh * 256 + kq * 8;
        #pragma unroll
        for (int ks = 0; ks < 8; ++ks) {
            short8 hi, md, lo;
            #pragma unroll
            for (int j = 0; j < 8; ++j) {
                float f = wp[ks * 32 + j];
                unsigned short h = f2bf_rne(f);
                float r1 = f - bf2f(h);
                unsigned short m = f2bf_rne(r1);
                float r2 = r1 - bf2f(m);
                hi[j] = (short)h;
                md[j] = (short)m;
                lo[j] = (short)f2bf_rne(r2);
            }
            whi[ks] = hi; wmd[ks] = md; wlo[ks] = lo;
        }
    }

    // ---- LIF state (kh==0 waves), C-layout: b = b0+kq*4+r, g = gw+mrow
    float v[4]  = {0.f, 0.f, 0.f, 0.f};
    float cu[4] = {0.f, 0.f, 0.f, 0.f};
    float zf[4] = {0.f, 0.f, 0.f, 0.f};

    // staging: thread owns dword (srow, swd): row srow, elements swd*32..+31.
    const int srow = tid & 15;
    const int swd  = tid >> 4;
    const unsigned* bp = bits + (size_t)(b0 + srow) * 16 + swd;  // +4096/t
    unsigned short* srow_base = &sA[srow * ROWP + swd * 32];

    unsigned wcur = bp[0];
    unsigned wnxt = bp[4096];

    for (int t = 0; t < T_STEPS; ++t) {
        // unpack 32 bits -> 32 bf16 -> 4 x ds_write_b128
        // d = ((t8|(t8<<15)) >> 2i & 0x10001) * 0x3F80 : two bf16 per dword
        #pragma unroll
        for (int q = 0; q < 4; ++q) {
            unsigned t8 = (wcur >> (8 * q)) & 0xFFu;
            unsigned u  = t8 | (t8 << 15);
            uintx4 d;
            d[0] = ( u        & 0x10001u) * 0x3F80u;
            d[1] = ((u >> 2)  & 0x10001u) * 0x3F80u;
            d[2] = ((u >> 4)  & 0x10001u) * 0x3F80u;
            d[3] = ((u >> 6)  & 0x10001u) * 0x3F80u;
            *(uintx4*)(srow_base + q * 8) = d;
        }
        __syncthreads();                          // barrier1: sA(t) ready
        wcur = wnxt;
        if (t + 2 < T_STEPS) wnxt = bp[(size_t)(t + 2) * 4096];

        floatx4 ah = {0.f, 0.f, 0.f, 0.f};
        floatx4 am = {0.f, 0.f, 0.f, 0.f};
        floatx4 al = {0.f, 0.f, 0.f, 0.f};
        const unsigned short* arow = &sA[mrow * ROWP + kh * 256 + kq * 8];
        #pragma unroll
        for (int ks = 0; ks < 8; ++ks) {
            short8 a = *(const short8*)(arow + ks * 32);
            ah = __builtin_amdgcn_mfma_f32_16x16x32_bf16(a, whi[ks], ah, 0, 0, 0);
            am = __builtin_amdgcn_mfma_f32_16x16x32_bf16(a, wmd[ks], am, 0, 0, 0);
            al = __builtin_amdgcn_mfma_f32_16x16x32_bf16(a, wlo[ks], al, 0, 0, 0);
        }

        if (kh == 1) {
            floatx4 xp = (ah + am) + al;
            *(floatx4*)&xbuf[gh * 256 + lane * 4] = xp;
        }
        __syncthreads();                          // barrier2: xbuf ready
        if (kh == 0) {
            floatx4 other = *(const floatx4*)&xbuf[gh * 256 + lane * 4];
            #pragma unroll
            for (int r = 0; r < 4; ++r) {
                float x    = ((ah[r] + am[r]) + al[r]) + other[r];
                float vdec = v[r] + 0.1f * ((0.0f - v[r]) + cu[r]);  // DT*TAU_MEM_INV
                float idec = cu[r] - 0.2f * cu[r];                    // DT*TAU_SYN_INV
                bool  spk  = (vdec - 1.0f) > 0.0f;                    // heaviside
                zf[r] = spk ? 1.0f : 0.0f;
                v[r]  = spk ? 0.0f : vdec;                            // V_RESET = 0
                cu[r] = idec + x;
            }
        }
        // next-iter barrier1 orders kh0's xbuf read before kh1's next write,
        // and sA(t) frag reads (pre-barrier2) before sA(t+1) stores.
    }

    if (kh == 0) {
        #pragma unroll
        for (int r = 0; r < 4; ++r) {
            const size_t idx = (size_t)(b0 + kq * 4 + r) * F_DIM + gw + mrow;
            out[idx]          = zf[r];
            out[BF + idx]     = v[r];
            out[2 * BF + idx] = cu[r];
        }
    }
}

// ---------------- fallback: R3 fp32-input kernel (verified) ----------------
__global__ __launch_bounds__(256, 1)
void lif_kernel_f32(const float* __restrict__ spikes,
                    const float* __restrict__ W,
                    float* __restrict__ out)
{
    __shared__ unsigned short sA[16 * ROWP];
    __shared__ float xbuf[2 * 256];

    const int tid  = threadIdx.x;
    const int lane = tid & 63;
    const int w    = tid >> 6;
    const int gh   = w & 1;
    const int kh   = w >> 1;
    const int bt   = blockIdx.x & 15;
    const int gb   = blockIdx.x >> 4;
    const int b0   = bt * 16;
    const int gw   = gb * 32 + gh * 16;
    const int mrow = lane & 15;
    const int kq   = lane >> 4;

    short8 whi[8], wmd[8], wlo[8];
    {
        const float* wp = W + (size_t)(gw + mrow) * F_DIM + kh * 256 + kq * 8;
        #pragma unroll
        for (int ks = 0; ks < 8; ++ks) {
            short8 hi, md, lo;
            #pragma unroll
            for (int j = 0; j < 8; ++j) {
                float f = wp[ks * 32 + j];
                unsigned short h = f2bf_rne(f);
                float r1 = f - bf2f(h);
                unsigned short m = f2bf_rne(r1);
                float r2 = r1 - bf2f(m);
                hi[j] = (short)h;
                md[j] = (short)m;
                lo[j] = (short)f2bf_rne(r2);
            }
            whi[ks] = hi; wmd[ks] = md; wlo[ks] = lo;
        }
    }

    float v[4]  = {0.f, 0.f, 0.f, 0.f};
    float cu[4] = {0.f, 0.f, 0.f, 0.f};
    float zf[4] = {0.f, 0.f, 0.f, 0.f};

    floatx4 ld[8];
    auto issue_loads = [&](int t) {
        const floatx4* sp = (const floatx4*)(spikes + (size_t)t * BF + (size_t)b0 * F_DIM);
        #pragma unroll
        for (int j = 0; j < 8; ++j)
            ld[j] = sp[tid + 256 * j];
    };

    issue_loads(0);
    for (int t = 0; t < T_STEPS; ++t) {
        #pragma unroll
        for (int j = 0; j < 8; ++j) {
            const int q = tid + 256 * j;
            const int row = q >> 7, col4 = q & 127;
            unsigned u0 = __float_as_uint(ld[j][0]);
            unsigned u1 = __float_as_uint(ld[j][1]);
            unsigned u2 = __float_as_uint(ld[j][2]);
            unsigned u3 = __float_as_uint(ld[j][3]);
            uintx2 d;
            d[0] = (u0 >> 16) | (u1 & 0xFFFF0000u);
            d[1] = (u2 >> 16) | (u3 & 0xFFFF0000u);
            *(uintx2*)&sA[row * ROWP + col4 * 4] = d;
        }
        __syncthreads();
        if (t + 1 < T_STEPS) issue_loads(t + 1);

        floatx4 ah = {0.f, 0.f, 0.f, 0.f};
        floatx4 am = {0.f, 0.f, 0.f, 0.f};
        floatx4 al = {0.f, 0.f, 0.f, 0.f};
        const unsigned short* arow = &sA[mrow * ROWP + kh * 256 + kq * 8];
        #pragma unroll
        for (int ks = 0; ks < 8; ++ks) {
            short8 a = *(const short8*)(arow + ks * 32);
            ah = __builtin_amdgcn_mfma_f32_16x16x32_bf16(a, whi[ks], ah, 0, 0, 0);
            am = __builtin_amdgcn_mfma_f32_16x16x32_bf16(a, wmd[ks], am, 0, 0, 0);
            al = __builtin_amdgcn_mfma_f32_16x16x32_bf16(a, wlo[ks], al, 0, 0, 0);
        }

        if (kh == 1) {
            floatx4 xp = (ah + am) + al;
            *(floatx4*)&xbuf[gh * 256 + lane * 4] = xp;
        }
        __syncthreads();
        if (kh == 0) {
            floatx4 other = *(const floatx4*)&xbuf[gh * 256 + lane * 4];
            #pragma unroll
            for (int r = 0; r < 4; ++r) {
                float x    = ((ah[r] + am[r]) + al[r]) + other[r];
                float vdec = v[r] + 0.1f * ((0.0f - v[r]) + cu[r]);
                float idec = cu[r] - 0.2f * cu[r];
                bool  spk  = (vdec - 1.0f) > 0.0f;
                zf[r] = spk ? 1.0f : 0.0f;
                v[r]  = spk ? 0.0f : vdec;
                cu[r] = idec + x;
            }
        }
    }

    if (kh == 0) {
        #pragma unroll
        for (int r = 0; r < 4; ++r) {
            const size_t idx = (size_t)(b0 + kq * 4 + r) * F_DIM + gw + mrow;
            out[idx]          = zf[r];
            out[BF + idx]     = v[r];
            out[2 * BF + idx] = cu[r];
        }
    }
}

extern "C" void kernel_launch(void* const* d_in, const int* in_sizes, int n_in,
                              void* d_out, int out_size, void* d_ws, size_t ws_size,
                              hipStream_t stream)
{
    const float* spikes = (const float*)d_in[0];   // [T,B,F] fp32
    const float* W      = (const float*)d_in[1];   // [F,F]   fp32
    float* out          = (float*)d_out;           // [3,B,F] fp32

    const size_t need = (size_t)T_STEPS * B_DIM * (F_DIM / 8);  // 16 MiB bitmask
    if (d_ws != nullptr && ws_size >= need) {
        unsigned* bits = (unsigned*)d_ws;
        pack_kernel<<<dim3(2048), dim3(256), 0, stream>>>(spikes, bits);
        lif_kernel_bits<<<dim3(256), dim3(256), 0, stream>>>(bits, W, out);
    } else {
        lif_kernel_f32<<<dim3(256), dim3(256), 0, stream>>>(spikes, W, out);
    }
}

// Round 3
// 1341.970 us; speedup vs baseline: 1.2832x; 1.0217x over previous
//
#include <hip/hip_runtime.h>
#include <hip/hip_bf16.h>

// LIF fused kernel, Round 6: single-barrier software-pipelined t-loop.
//
// R5 post-mortem: bit-pack worked (FETCH 266->12 MB, main 1236->730us) but
// main kernel is phase-serialized at 1 wave/SIMD: [unpack+write] bar1
// [MFMA] [xbuf] bar2 [LIF] exposes every latency serially; MFMA floor is
// only 466 cy/t of the measured 1710 cy/t.
//
// R6 structure: double-buffer sA and xbuf, ping-pong accumulator register
// sets (A/B, loop unrolled x2 for static reg indexing), ONE barrier per t:
//   iter t: [kh0: deferred LIF(t-1) from prev acc + xbuf[(t-1)&1]]
//           unpack(t+1) -> sA[(t+1)&1]   (no barrier needed: other buffer)
//           MFMA(t) from sA[t&1]         (compiler interleaves with unpack)
//           [kh1: xbuf[t&1] = partial]
//           __syncthreads()
// Numerics bit-identical to R5 (same split/order); absmax expected 0.001953.
//
// Packed layout: bits[t*4096 + b*16 + wd], bit j (LSB first) =
// spike[t][b][wd*32+j] != 0.

typedef __attribute__((ext_vector_type(8))) short short8;   // 8 x bf16
typedef __attribute__((ext_vector_type(4))) float floatx4;
typedef __attribute__((ext_vector_type(2))) unsigned uintx2;
typedef __attribute__((ext_vector_type(4))) unsigned uintx4;

#define T_STEPS 1024
#define B_DIM   256
#define F_DIM   512
#define BF      (B_DIM * F_DIM)
#define ROWP    520   // padded LDS row (bf16 units); 1040B = 16B-aligned rows

static __device__ __forceinline__ unsigned short f2bf_rne(float f) {
    unsigned u = __float_as_uint(f);
    return (unsigned short)((u + 0x7FFFu + ((u >> 16) & 1u)) >> 16);
}
static __device__ __forceinline__ float bf2f(unsigned short h) {
    return __uint_as_float(((unsigned)h) << 16);
}

// ---------------- prepass: fp32 {0,1} -> bitmask ----------------
__global__ __launch_bounds__(256)
void pack_kernel(const float* __restrict__ sp, unsigned* __restrict__ bits)
{
    const int lane = threadIdx.x & 63;
    const int wv   = blockIdx.x * 4 + (threadIdx.x >> 6);
    for (int c = wv; c < 65536; c += 2048 * 4) {
        const float* p = sp + (size_t)c * 2048;
        unsigned val = 0;
        #pragma unroll
        for (int r = 0; r < 32; ++r) {
            float x = p[r * 64 + lane];
            unsigned long long m = __ballot(x != 0.0f);
            unsigned sel = (lane & 1) ? (unsigned)(m >> 32) : (unsigned)m;
            if ((lane >> 1) == r) val = sel;
        }
        bits[(size_t)c * 64 + lane] = val;
    }
}

// ---------------- main kernel: bitmask input, 1 barrier/t ----------------
__global__ __launch_bounds__(256, 1)
void lif_kernel_bits(const unsigned* __restrict__ bits,
                     const float* __restrict__ W,
                     float* __restrict__ out)
{
    __shared__ unsigned short sA[2][16 * ROWP];   // double-buffered bf16 A-slab
    __shared__ float xbuf[2][2 * 256];            // double-buffered kh=1 partials

    const int tid  = threadIdx.x;
    const int lane = tid & 63;
    const int w    = tid >> 6;      // 0..3
    const int gh   = w & 1;         // g-half within block
    const int kh   = w >> 1;        // K-half
    const int bt   = blockIdx.x & 15;
    const int gb   = blockIdx.x >> 4;
    const int b0   = bt * 16;
    const int gw   = gb * 32 + gh * 16;   // wave's g-base
    const int mrow = lane & 15;
    const int kq   = lane >> 4;

    // ---- W fragments (once): rows gw+mrow, k in kh*256 + ks*32 + kq*8 + j
    short8 whi[8], wmd[8], wlo[8];
    {
        const float* wp = W + (size_t)(gw + mrow) * F_DIM + kh * 256 + kq * 8;
        #pragma unroll
        for (int ks = 0; ks < 8; ++ks) {
            short8 hi, md, lo;
            #pragma unroll
            for (int j = 0; j < 8; ++j) {
                float f = wp[ks * 32 + j];
                unsigned short h = f2bf_rne(f);
                float r1 = f - bf2f(h);
                unsigned short m = f2bf_rne(r1);
                float r2 = r1 - bf2f(m);
                hi[j] = (short)h;
                md[j] = (short)m;
                lo[j] = (short)f2bf_rne(r2);
            }
            whi[ks] = hi; wmd[ks] = md; wlo[ks] = lo;
        }
    }

    // ---- LIF state (kh==0 waves), C-layout: b = b0+kq*4+r, g = gw+mrow
    float v[4]  = {0.f, 0.f, 0.f, 0.f};
    float cu[4] = {0.f, 0.f, 0.f, 0.f};
    float zf[4] = {0.f, 0.f, 0.f, 0.f};

    // staging: thread owns dword (srow, swd): row srow, elements swd*32..+31.
    const int srow = tid & 15;
    const int swd  = tid >> 4;
    const unsigned* bp = bits + (size_t)(b0 + srow) * 16 + swd;  // +4096/t
    unsigned short* s0 = &sA[0][srow * ROWP + swd * 32];
    unsigned short* s1 = &sA[1][srow * ROWP + swd * 32];
    const unsigned short* a0 = &sA[0][mrow * ROWP + kh * 256 + kq * 8];
    const unsigned short* a1 = &sA[1][mrow * ROWP + kh * 256 + kq * 8];
    const int xoff = gh * 256 + lane * 4;

    // unpack 32 bits -> 32 bf16 -> 4 x ds_write_b128
    auto unpack_to = [&](unsigned wbits, unsigned short* dst) {
        #pragma unroll
        for (int q = 0; q < 4; ++q) {
            unsigned t8 = (wbits >> (8 * q)) & 0xFFu;
            unsigned u  = t8 | (t8 << 15);
            uintx4 d;
            d[0] = ( u        & 0x10001u) * 0x3F80u;
            d[1] = ((u >> 2)  & 0x10001u) * 0x3F80u;
            d[2] = ((u >> 4)  & 0x10001u) * 0x3F80u;
            d[3] = ((u >> 6)  & 0x10001u) * 0x3F80u;
            *(uintx4*)(dst + q * 8) = d;
        }
    };

    auto mfma_acc = [&](const unsigned short* arow,
                        floatx4& ah, floatx4& am, floatx4& al) {
        #pragma unroll
        for (int ks = 0; ks < 8; ++ks) {
            short8 a = *(const short8*)(arow + ks * 32);
            ah = __builtin_amdgcn_mfma_f32_16x16x32_bf16(a, whi[ks], ah, 0, 0, 0);
            am = __builtin_amdgcn_mfma_f32_16x16x32_bf16(a, wmd[ks], am, 0, 0, 0);
            al = __builtin_amdgcn_mfma_f32_16x16x32_bf16(a, wlo[ks], al, 0, 0, 0);
        }
    };

    auto lif_step = [&](const floatx4& ah, const floatx4& am, const floatx4& al,
                        const float* xb) {
        floatx4 other = *(const floatx4*)xb;
        #pragma unroll
        for (int r = 0; r < 4; ++r) {
            float x    = ((ah[r] + am[r]) + al[r]) + other[r];
            float vdec = v[r] + 0.1f * ((0.0f - v[r]) + cu[r]);  // DT*TAU_MEM_INV
            float idec = cu[r] - 0.2f * cu[r];                    // DT*TAU_SYN_INV
            bool  spk  = (vdec - 1.0f) > 0.0f;                    // heaviside
            zf[r] = spk ? 1.0f : 0.0f;
            v[r]  = spk ? 0.0f : vdec;                            // V_RESET = 0
            cu[r] = idec + x;
        }
    };

    const floatx4 fz = {0.f, 0.f, 0.f, 0.f};
    floatx4 ahA = fz, amA = fz, alA = fz;   // even-t accumulators
    floatx4 ahB = fz, amB = fz, alB = fz;   // odd-t accumulators

    // ---- prologue: stage t=0 into sA[0]; bits pipeline depth 2
    unsigned wcur = bp[0];
    unsigned wnxt = bp[4096];
    unpack_to(wcur, s0);        // slab t=0
    wcur = wnxt;                // bits t=1
    wnxt = bp[2 * 4096];        // bits t=2
    __syncthreads();            // sA[0] ready

    for (int t = 0; t < T_STEPS; t += 2) {
        // ======== even iter: compute t (sA[0]), stage t+1 -> sA[1] ========
        if (kh == 0 && t > 0)
            lif_step(ahB, amB, alB, &xbuf[1][xoff]);   // LIF(t-1)
        ahA = fz; amA = fz; alA = fz;
        unpack_to(wcur, s1);                           // t+1 <= 1023 always
        wcur = wnxt;
        if (t + 3 < T_STEPS) wnxt = bp[(size_t)(t + 3) * 4096];
        mfma_acc(a0, ahA, amA, alA);
        if (kh == 1) {
            floatx4 xp = (ahA + amA) + alA;
            *(floatx4*)&xbuf[0][xoff] = xp;
        }
        __syncthreads();   // sA[1] ready; xbuf[0] ready; sA[0] reads done

        // ======== odd iter: compute t+1 (sA[1]), stage t+2 -> sA[0] =======
        if (kh == 0)
            lif_step(ahA, amA, alA, &xbuf[0][xoff]);   // LIF(t)
        ahB = fz; amB = fz; alB = fz;
        if (t + 2 < T_STEPS) unpack_to(wcur, s0);
        wcur = wnxt;
        if (t + 4 < T_STEPS) wnxt = bp[(size_t)(t + 4) * 4096];
        mfma_acc(a1, ahB, amB, alB);
        if (kh == 1) {
            floatx4 xp = (ahB + amB) + alB;
            *(floatx4*)&xbuf[1][xoff] = xp;
        }
        __syncthreads();   // sA[0] ready; xbuf[1] ready; sA[1] reads done
    }
    // epilogue: LIF for t = 1023 (odd, B accumulators)
    if (kh == 0)
        lif_step(ahB, amB, alB, &xbuf[1][xoff]);

    if (kh == 0) {
        #pragma unroll
        for (int r = 0; r < 4; ++r) {
            const size_t idx = (size_t)(b0 + kq * 4 + r) * F_DIM + gw + mrow;
            out[idx]          = zf[r];
            out[BF + idx]     = v[r];
            out[2 * BF + idx] = cu[r];
        }
    }
}

// ---------------- fallback: R3 fp32-input kernel (verified) ----------------
__global__ __launch_bounds__(256, 1)
void lif_kernel_f32(const float* __restrict__ spikes,
                    const float* __restrict__ W,
                    float* __restrict__ out)
{
    __shared__ unsigned short sAf[16 * ROWP];
    __shared__ float xbuf[2 * 256];

    const int tid  = threadIdx.x;
    const int lane = tid & 63;
    const int w    = tid >> 6;
    const int gh   = w & 1;
    const int kh   = w >> 1;
    const int bt   = blockIdx.x & 15;
    const int gb   = blockIdx.x >> 4;
    const int b0   = bt * 16;
    const int gw   = gb * 32 + gh * 16;
    const int mrow = lane & 15;
    const int kq   = lane >> 4;

    short8 whi[8], wmd[8], wlo[8];
    {
        const float* wp = W + (size_t)(gw + mrow) * F_DIM + kh * 256 + kq * 8;
        #pragma unroll
        for (int ks = 0; ks < 8; ++ks) {
            short8 hi, md, lo;
            #pragma unroll
            for (int j = 0; j < 8; ++j) {
                float f = wp[ks * 32 + j];
                unsigned short h = f2bf_rne(f);
                float r1 = f - bf2f(h);
                unsigned short m = f2bf_rne(r1);
                float r2 = r1 - bf2f(m);
                hi[j] = (short)h;
                md[j] = (short)m;
                lo[j] = (short)f2bf_rne(r2);
            }
            whi[ks] = hi; wmd[ks] = md; wlo[ks] = lo;
        }
    }

    float v[4]  = {0.f, 0.f, 0.f, 0.f};
    float cu[4] = {0.f, 0.f, 0.f, 0.f};
    float zf[4] = {0.f, 0.f, 0.f, 0.f};

    floatx4 ld[8];
    auto issue_loads = [&](int t) {
        const floatx4* sp = (const floatx4*)(spikes + (size_t)t * BF + (size_t)b0 * F_DIM);
        #pragma unroll
        for (int j = 0; j < 8; ++j)
            ld[j] = sp[tid + 256 * j];
    };

    issue_loads(0);
    for (int t = 0; t < T_STEPS; ++t) {
        #pragma unroll
        for (int j = 0; j < 8; ++j) {
            const int q = tid + 256 * j;
            const int row = q >> 7, col4 = q & 127;
            unsigned u0 = __float_as_uint(ld[j][0]);
            unsigned u1 = __float_as_uint(ld[j][1]);
            unsigned u2 = __float_as_uint(ld[j][2]);
            unsigned u3 = __float_as_uint(ld[j][3]);
            uintx2 d;
            d[0] = (u0 >> 16) | (u1 & 0xFFFF0000u);
            d[1] = (u2 >> 16) | (u3 & 0xFFFF0000u);
            *(uintx2*)&sAf[row * ROWP + col4 * 4] = d;
        }
        __syncthreads();
        if (t + 1 < T_STEPS) issue_loads(t + 1);

        floatx4 ah = {0.f, 0.f, 0.f, 0.f};
        floatx4 am = {0.f, 0.f, 0.f, 0.f};
        floatx4 al = {0.f, 0.f, 0.f, 0.f};
        const unsigned short* arow = &sAf[mrow * ROWP + kh * 256 + kq * 8];
        #pragma unroll
        for (int ks = 0; ks < 8; ++ks) {
            short8 a = *(const short8*)(arow + ks * 32);
            ah = __builtin_amdgcn_mfma_f32_16x16x32_bf16(a, whi[ks], ah, 0, 0, 0);
            am = __builtin_amdgcn_mfma_f32_16x16x32_bf16(a, wmd[ks], am, 0, 0, 0);
            al = __builtin_amdgcn_mfma_f32_16x16x32_bf16(a, wlo[ks], al, 0, 0, 0);
        }

        if (kh == 1) {
            floatx4 xp = (ah + am) + al;
            *(floatx4*)&xbuf[gh * 256 + lane * 4] = xp;
        }
        __syncthreads();
        if (kh == 0) {
            floatx4 other = *(const floatx4*)&xbuf[gh * 256 + lane * 4];
            #pragma unroll
            for (int r = 0; r < 4; ++r) {
                float x    = ((ah[r] + am[r]) + al[r]) + other[r];
                float vdec = v[r] + 0.1f * ((0.0f - v[r]) + cu[r]);
                float idec = cu[r] - 0.2f * cu[r];
                bool  spk  = (vdec - 1.0f) > 0.0f;
                zf[r] = spk ? 1.0f : 0.0f;
                v[r]  = spk ? 0.0f : vdec;
                cu[r] = idec + x;
            }
        }
    }

    if (kh == 0) {
        #pragma unroll
        for (int r = 0; r < 4; ++r) {
            const size_t idx = (size_t)(b0 + kq * 4 + r) * F_DIM + gw + mrow;
            out[idx]          = zf[r];
            out[BF + idx]     = v[r];
            out[2 * BF + idx] = cu[r];
        }
    }
}

extern "C" void kernel_launch(void* const* d_in, const int* in_sizes, int n_in,
                              void* d_out, int out_size, void* d_ws, size_t ws_size,
                              hipStream_t stream)
{
    const float* spikes = (const float*)d_in[0];   // [T,B,F] fp32
    const float* W      = (const float*)d_in[1];   // [F,F]   fp32
    float* out          = (float*)d_out;           // [3,B,F] fp32

    const size_t need = (size_t)T_STEPS * B_DIM * (F_DIM / 8);  // 16 MiB bitmask
    if (d_ws != nullptr && ws_size >= need) {
        unsigned* bits = (unsigned*)d_ws;
        pack_kernel<<<dim3(2048), dim3(256), 0, stream>>>(spikes, bits);
        lif_kernel_bits<<<dim3(256), dim3(256), 0, stream>>>(bits, W, out);
    } else {
        lif_kernel_f32<<<dim3(256), dim3(256), 0, stream>>>(spikes, W, out);
    }
}

// Round 4
// 1214.244 us; speedup vs baseline: 1.4182x; 1.1052x over previous
//
#include <hip/hip_runtime.h>
#include <hip/hip_bf16.h>

// LIF fused kernel, Round 7: 2 waves/SIMD via 8-wave blocks (K-quarters).
//
// R6 post-mortem: single-barrier restructure was neutral (730->697us) ->
// the cost was never barrier count; it's latency exposure at 1 wave/SIMD
// (one dependence chain, nothing to fill lgkmcnt/MFMA-latency bubbles).
// MFMA floor 466 cy/t vs measured 1634 cy/t.
//
// R7: 512-thread blocks, 8 waves = (gh 0/1) x (K-quarter wq 0..3).
// 12 MFMA/wave/t, W frags 48 VGPR/wave, 2 waves/SIMD -> second stream
// hides LDS/VALU/latency under MFMA. Double-buffered sA + xbuf, ONE
// barrier/t, deferred LIF (wq0 reduces 3 xbuf partials + own acc).
// Unpack mul replaced by exact shift-sub: x*0x3F80 = (x<<14)-(x<<7)
// for x in {0,1,0x10000,0x10001} (no cross-half borrow).
//
// Packed layout: bits[t*4096 + b*16 + wd], bit j (LSB) = spike[t][b][wd*32+j].

typedef __attribute__((ext_vector_type(8))) short short8;   // 8 x bf16
typedef __attribute__((ext_vector_type(4))) float floatx4;
typedef __attribute__((ext_vector_type(2))) unsigned uintx2;
typedef __attribute__((ext_vector_type(4))) unsigned uintx4;

#define T_STEPS 1024
#define B_DIM   256
#define F_DIM   512
#define BF      (B_DIM * F_DIM)
#define ROWP    520   // padded LDS row (bf16 units); 1040B = 16B-aligned rows

static __device__ __forceinline__ unsigned short f2bf_rne(float f) {
    unsigned u = __float_as_uint(f);
    return (unsigned short)((u + 0x7FFFu + ((u >> 16) & 1u)) >> 16);
}
static __device__ __forceinline__ float bf2f(unsigned short h) {
    return __uint_as_float(((unsigned)h) << 16);
}

// ---------------- prepass: fp32 {0,1} -> bitmask ----------------
__global__ __launch_bounds__(256)
void pack_kernel(const float* __restrict__ sp, unsigned* __restrict__ bits)
{
    const int lane = threadIdx.x & 63;
    const int wv   = blockIdx.x * 4 + (threadIdx.x >> 6);
    for (int c = wv; c < 65536; c += 2048 * 4) {
        const float* p = sp + (size_t)c * 2048;
        unsigned val = 0;
        #pragma unroll
        for (int r = 0; r < 32; ++r) {
            float x = p[r * 64 + lane];
            unsigned long long m = __ballot(x != 0.0f);
            unsigned sel = (lane & 1) ? (unsigned)(m >> 32) : (unsigned)m;
            if ((lane >> 1) == r) val = sel;
        }
        bits[(size_t)c * 64 + lane] = val;
    }
}

// ---------------- main kernel: 8 waves, K-quarters, 1 barrier/t ----------
__global__ __launch_bounds__(512, 2)
void lif_kernel_bits(const unsigned* __restrict__ bits,
                     const float* __restrict__ W,
                     float* __restrict__ out)
{
    __shared__ unsigned short sA[2][16 * ROWP];   // double-buffered bf16 A-slab
    __shared__ float xbuf[2][6 * 256];            // dbuf x (wq1..3 x gh) partials

    const int tid  = threadIdx.x;
    const int lane = tid & 63;
    const int w    = tid >> 6;      // 0..7
    const int gh   = w & 1;         // g-half within block
    const int wq   = w >> 1;        // K-quarter 0..3
    const int bt   = blockIdx.x & 15;
    const int gb   = blockIdx.x >> 4;
    const int b0   = bt * 16;
    const int gw   = gb * 32 + gh * 16;   // wave's g-base
    const int mrow = lane & 15;
    const int lq   = lane >> 4;

    // ---- W fragments (once): rows gw+mrow, k = wq*128 + ks*32 + lq*8 + j
    short8 whi[4], wmd[4], wlo[4];
    {
        const float* wp = W + (size_t)(gw + mrow) * F_DIM + wq * 128 + lq * 8;
        #pragma unroll
        for (int ks = 0; ks < 4; ++ks) {
            short8 hi, md, lo;
            #pragma unroll
            for (int j = 0; j < 8; ++j) {
                float f = wp[ks * 32 + j];
                unsigned short h = f2bf_rne(f);
                float r1 = f - bf2f(h);
                unsigned short m = f2bf_rne(r1);
                float r2 = r1 - bf2f(m);
                hi[j] = (short)h;
                md[j] = (short)m;
                lo[j] = (short)f2bf_rne(r2);
            }
            whi[ks] = hi; wmd[ks] = md; wlo[ks] = lo;
        }
    }

    // ---- LIF state (wq==0 waves), C-layout: b = b0+lq*4+r, g = gw+mrow
    float v[4]  = {0.f, 0.f, 0.f, 0.f};
    float cu[4] = {0.f, 0.f, 0.f, 0.f};
    float zf[4] = {0.f, 0.f, 0.f, 0.f};

    // staging: thread owns 16 bits: row srow, elems [shalf*16, shalf*16+16)
    const int srow  = tid & 15;
    const int shalf = tid >> 4;                    // 0..31
    const int hsh   = (shalf & 1) * 16;            // which half of the dword
    const unsigned* bp = bits + (size_t)(b0 + srow) * 16 + (shalf >> 1); // +4096/t
    unsigned short* s0 = &sA[0][srow * ROWP + shalf * 16];
    unsigned short* s1 = &sA[1][srow * ROWP + shalf * 16];
    const unsigned short* a0 = &sA[0][mrow * ROWP + wq * 128 + lq * 8];
    const unsigned short* a1 = &sA[1][mrow * ROWP + wq * 128 + lq * 8];
    // partial-x slots (wq>=1 write; wq==0 reads all three)
    float* xw0 = &xbuf[0][((wq - 1) * 2 + gh) * 256 + lane * 4];
    float* xw1 = &xbuf[1][((wq - 1) * 2 + gh) * 256 + lane * 4];
    const int xr = gh * 256 + lane * 4;   // + p*512 for partial p

    // unpack 16 bits -> 16 bf16 -> 2 x ds_write_b128
    // per dword: x = (u>>2i)&0x10001; d = (x<<14)-(x<<7)  (== x*0x3F80)
    auto unpack_to = [&](unsigned dw, unsigned short* dst) {
        unsigned h16 = (dw >> hsh) & 0xFFFFu;
        #pragma unroll
        for (int q = 0; q < 2; ++q) {
            unsigned t8 = (h16 >> (8 * q)) & 0xFFu;
            unsigned u  = t8 | (t8 << 15);
            unsigned x0 =  u        & 0x10001u;
            unsigned x1 = (u >> 2)  & 0x10001u;
            unsigned x2 = (u >> 4)  & 0x10001u;
            unsigned x3 = (u >> 6)  & 0x10001u;
            uintx4 d;
            d[0] = (x0 << 14) - (x0 << 7);
            d[1] = (x1 << 14) - (x1 << 7);
            d[2] = (x2 << 14) - (x2 << 7);
            d[3] = (x3 << 14) - (x3 << 7);
            *(uintx4*)(dst + q * 8) = d;
        }
    };

    auto mfma_acc = [&](const unsigned short* arow,
                        floatx4& ah, floatx4& am, floatx4& al) {
        #pragma unroll
        for (int ks = 0; ks < 4; ++ks) {
            short8 a = *(const short8*)(arow + ks * 32);
            ah = __builtin_amdgcn_mfma_f32_16x16x32_bf16(a, whi[ks], ah, 0, 0, 0);
            am = __builtin_amdgcn_mfma_f32_16x16x32_bf16(a, wmd[ks], am, 0, 0, 0);
            al = __builtin_amdgcn_mfma_f32_16x16x32_bf16(a, wlo[ks], al, 0, 0, 0);
        }
    };

    auto lif_step = [&](const floatx4& ah, const floatx4& am, const floatx4& al,
                        const float* xb) {
        floatx4 p1 = *(const floatx4*)(xb + xr);
        floatx4 p2 = *(const floatx4*)(xb + xr + 512);
        floatx4 p3 = *(const floatx4*)(xb + xr + 1024);
        #pragma unroll
        for (int r = 0; r < 4; ++r) {
            float own  = (ah[r] + am[r]) + al[r];
            float x    = ((own + p1[r]) + p2[r]) + p3[r];
            float vdec = v[r] + 0.1f * ((0.0f - v[r]) + cu[r]);  // DT*TAU_MEM_INV
            float idec = cu[r] - 0.2f * cu[r];                    // DT*TAU_SYN_INV
            bool  spk  = (vdec - 1.0f) > 0.0f;                    // heaviside
            zf[r] = spk ? 1.0f : 0.0f;
            v[r]  = spk ? 0.0f : vdec;                            // V_RESET = 0
            cu[r] = idec + x;
        }
    };

    const floatx4 fz = {0.f, 0.f, 0.f, 0.f};
    floatx4 ahA = fz, amA = fz, alA = fz;   // even-t accumulators
    floatx4 ahB = fz, amB = fz, alB = fz;   // odd-t accumulators

    // ---- prologue: stage t=0 into sA[0]; bits pipeline depth 2
    unsigned wcur = bp[0];
    unpack_to(wcur, s0);        // slab t=0
    wcur = bp[4096];            // bits t=1
    unsigned wnxt = bp[2 * 4096];  // bits t=2
    __syncthreads();            // sA[0] ready

    for (int t = 0; t < T_STEPS; t += 2) {
        // ======== even: compute t (sA[0]), stage t+1 -> sA[1] ========
        if (wq == 0 && t > 0)
            lif_step(ahB, amB, alB, &xbuf[1][0]);   // LIF(t-1)
        ahA = fz; amA = fz; alA = fz;
        unpack_to(wcur, s1);                        // t+1 <= 1023 always
        wcur = wnxt;
        if (t + 3 < T_STEPS) wnxt = bp[(size_t)(t + 3) * 4096];
        mfma_acc(a0, ahA, amA, alA);
        if (wq > 0)
            *(floatx4*)xw0 = (ahA + amA) + alA;
        __syncthreads();   // sA[1], xbuf[0] ready; sA[0]/xbuf[1] reads done

        // ======== odd: compute t+1 (sA[1]), stage t+2 -> sA[0] =======
        if (wq == 0)
            lif_step(ahA, amA, alA, &xbuf[0][0]);   // LIF(t)
        ahB = fz; amB = fz; alB = fz;
        if (t + 2 < T_STEPS) unpack_to(wcur, s0);
        wcur = wnxt;
        if (t + 4 < T_STEPS) wnxt = bp[(size_t)(t + 4) * 4096];
        mfma_acc(a1, ahB, amB, alB);
        if (wq > 0)
            *(floatx4*)xw1 = (ahB + amB) + alB;
        __syncthreads();   // sA[0], xbuf[1] ready; sA[1]/xbuf[0] reads done
    }
    // epilogue: LIF for t = 1023 (odd, B accumulators)
    if (wq == 0) {
        lif_step(ahB, amB, alB, &xbuf[1][0]);
        #pragma unroll
        for (int r = 0; r < 4; ++r) {
            const size_t idx = (size_t)(b0 + lq * 4 + r) * F_DIM + gw + mrow;
            out[idx]          = zf[r];
            out[BF + idx]     = v[r];
            out[2 * BF + idx] = cu[r];
        }
    }
}

// ---------------- fallback: R3 fp32-input kernel (verified) ----------------
__global__ __launch_bounds__(256, 1)
void lif_kernel_f32(const float* __restrict__ spikes,
                    const float* __restrict__ W,
                    float* __restrict__ out)
{
    __shared__ unsigned short sAf[16 * ROWP];
    __shared__ float xbuf[2 * 256];

    const int tid  = threadIdx.x;
    const int lane = tid & 63;
    const int w    = tid >> 6;
    const int gh   = w & 1;
    const int kh   = w >> 1;
    const int bt   = blockIdx.x & 15;
    const int gb   = blockIdx.x >> 4;
    const int b0   = bt * 16;
    const int gw   = gb * 32 + gh * 16;
    const int mrow = lane & 15;
    const int kq   = lane >> 4;

    short8 whi[8], wmd[8], wlo[8];
    {
        const float* wp = W + (size_t)(gw + mrow) * F_DIM + kh * 256 + kq * 8;
        #pragma unroll
        for (int ks = 0; ks < 8; ++ks) {
            short8 hi, md, lo;
            #pragma unroll
            for (int j = 0; j < 8; ++j) {
                float f = wp[ks * 32 + j];
                unsigned short h = f2bf_rne(f);
                float r1 = f - bf2f(h);
                unsigned short m = f2bf_rne(r1);
                float r2 = r1 - bf2f(m);
                hi[j] = (short)h;
                md[j] = (short)m;
                lo[j] = (short)f2bf_rne(r2);
            }
            whi[ks] = hi; wmd[ks] = md; wlo[ks] = lo;
        }
    }

    float v[4]  = {0.f, 0.f, 0.f, 0.f};
    float cu[4] = {0.f, 0.f, 0.f, 0.f};
    float zf[4] = {0.f, 0.f, 0.f, 0.f};

    floatx4 ld[8];
    auto issue_loads = [&](int t) {
        const floatx4* sp = (const floatx4*)(spikes + (size_t)t * BF + (size_t)b0 * F_DIM);
        #pragma unroll
        for (int j = 0; j < 8; ++j)
            ld[j] = sp[tid + 256 * j];
    };

    issue_loads(0);
    for (int t = 0; t < T_STEPS; ++t) {
        #pragma unroll
        for (int j = 0; j < 8; ++j) {
            const int q = tid + 256 * j;
            const int row = q >> 7, col4 = q & 127;
            unsigned u0 = __float_as_uint(ld[j][0]);
            unsigned u1 = __float_as_uint(ld[j][1]);
            unsigned u2 = __float_as_uint(ld[j][2]);
            unsigned u3 = __float_as_uint(ld[j][3]);
            uintx2 d;
            d[0] = (u0 >> 16) | (u1 & 0xFFFF0000u);
            d[1] = (u2 >> 16) | (u3 & 0xFFFF0000u);
            *(uintx2*)&sAf[row * ROWP + col4 * 4] = d;
        }
        __syncthreads();
        if (t + 1 < T_STEPS) issue_loads(t + 1);

        floatx4 ah = {0.f, 0.f, 0.f, 0.f};
        floatx4 am = {0.f, 0.f, 0.f, 0.f};
        floatx4 al = {0.f, 0.f, 0.f, 0.f};
        const unsigned short* arow = &sAf[mrow * ROWP + kh * 256 + kq * 8];
        #pragma unroll
        for (int ks = 0; ks < 8; ++ks) {
            short8 a = *(const short8*)(arow + ks * 32);
            ah = __builtin_amdgcn_mfma_f32_16x16x32_bf16(a, whi[ks], ah, 0, 0, 0);
            am = __builtin_amdgcn_mfma_f32_16x16x32_bf16(a, wmd[ks], am, 0, 0, 0);
            al = __builtin_amdgcn_mfma_f32_16x16x32_bf16(a, wlo[ks], al, 0, 0, 0);
        }

        if (kh == 1) {
            floatx4 xp = (ah + am) + al;
            *(floatx4*)&xbuf[gh * 256 + lane * 4] = xp;
        }
        __syncthreads();
        if (kh == 0) {
            floatx4 other = *(const floatx4*)&xbuf[gh * 256 + lane * 4];
            #pragma unroll
            for (int r = 0; r < 4; ++r) {
                float x    = ((ah[r] + am[r]) + al[r]) + other[r];
                float vdec = v[r] + 0.1f * ((0.0f - v[r]) + cu[r]);
                float idec = cu[r] - 0.2f * cu[r];
                bool  spk  = (vdec - 1.0f) > 0.0f;
                zf[r] = spk ? 1.0f : 0.0f;
                v[r]  = spk ? 0.0f : vdec;
                cu[r] = idec + x;
            }
        }
    }

    if (kh == 0) {
        #pragma unroll
        for (int r = 0; r < 4; ++r) {
            const size_t idx = (size_t)(b0 + kq * 4 + r) * F_DIM + gw + mrow;
            out[idx]          = zf[r];
            out[BF + idx]     = v[r];
            out[2 * BF + idx] = cu[r];
        }
    }
}

extern "C" void kernel_launch(void* const* d_in, const int* in_sizes, int n_in,
                              void* d_out, int out_size, void* d_ws, size_t ws_size,
                              hipStream_t stream)
{
    const float* spikes = (const float*)d_in[0];   // [T,B,F] fp32
    const float* W      = (const float*)d_in[1];   // [F,F]   fp32
    float* out          = (float*)d_out;           // [3,B,F] fp32

    const size_t need = (size_t)T_STEPS * B_DIM * (F_DIM / 8);  // 16 MiB bitmask
    if (d_ws != nullptr && ws_size >= need) {
        unsigned* bits = (unsigned*)d_ws;
        pack_kernel<<<dim3(2048), dim3(256), 0, stream>>>(spikes, bits);
        lif_kernel_bits<<<dim3(256), dim3(512), 0, stream>>>(bits, W, out);
    } else {
        lif_kernel_f32<<<dim3(256), dim3(256), 0, stream>>>(spikes, W, out);
    }
}